// Round 8
// baseline (297.147 us; speedup 1.0000x reference)
//
#include <hip/hip_runtime.h>
#include <math.h>

#define BB 4
#define NN 2048              // N == M
#define TPB 256
#define ROWS 16              // rows per block (one per thread tid&15)
#define GRPS 16              // column groups (grp = tid>>4)
#define CPG (NN/GRPS)        // 128 columns per group, interleaved stride GRPS
#define BPB (NN/ROWS)        // 128 blocks per batch
#define NBLK (BB*BPB)        // 512 blocks = 2 per CU
#define SLOT (BB*NN)         // 8192

#if __has_builtin(__builtin_amdgcn_exp2f)
  #define FEXP2(x) __builtin_amdgcn_exp2f(x)
#else
  #define FEXP2(x) exp2f(x)
#endif
#if __has_builtin(__builtin_amdgcn_sqrtf)
  #define FSQRT(x) __builtin_amdgcn_sqrtf(x)
#else
  #define FSQRT(x) sqrtf(x)
#endif

// ws float layout:
// [0]        ratL  [SLOT]
// [SLOT]     ratR  [SLOT]
// [2*SLOT]   remL  [SLOT]
// [3*SLOT]   remR  [SLOT]
// [4*SLOT]   costp [NBLK]

// Reduce per-thread partial v over the 16 groups of each row.
// After this, threads tid<16 hold the row totals (row = tid).
// red: [4 waves][16 rows] scratch.
#define ROW_REDUCE(v, red, tid)                                   \
    do {                                                          \
        (v) += __shfl_xor((v), 16, 64);                           \
        (v) += __shfl_xor((v), 32, 64);                           \
        if (((tid) & 63) < 16) red[(tid) >> 6][(tid) & 15] = (v); \
    } while (0)

// A0: ratL[n] = 1/(sum_m exp2(lvl2*d2)+1e-9)  (remL=remR=1 at level 0)
__global__ void k_A0(const float* __restrict__ tpl, const float* __restrict__ src,
                     float* __restrict__ ws, float lvl2) {
    __shared__ float4 sh4[NN];
    __shared__ float red[4][ROWS];
    int bid = blockIdx.x, tid = threadIdx.x;
    int b = bid / BPB, rc = bid % BPB;
    int row = tid & 15, grp = tid >> 4;
    int gbase = b*NN, g = gbase + rc*ROWS + row;
    float* ratL = ws;
    float* costp = ws + 4*SLOT;
    if (tid == 0) costp[bid] = 0.0f;
    for (int i = tid; i < NN; i += TPB) {
        const float* sp = src + (gbase + i)*3;
        sh4[i] = make_float4(sp[0], sp[1], sp[2], 0.0f);
    }
    __syncthreads();
    const float* tp = tpl + g*3;
    float x = tp[0], y = tp[1], z = tp[2];
    float a0 = 0.f, a1 = 0.f;
#pragma unroll 8
    for (int i = 0; i < CPG; i += 2) {
        int i0 = grp + (i << 4), i1 = i0 + GRPS;
        float4 s0 = sh4[i0];
        float4 s1 = sh4[i1];
        float dx0 = x-s0.x, dy0 = y-s0.y, dz0 = z-s0.z;
        float dx1 = x-s1.x, dy1 = y-s1.y, dz1 = z-s1.z;
        float d20 = dx0*dx0 + dy0*dy0 + dz0*dz0;
        float d21 = dx1*dx1 + dy1*dy1 + dz1*dz1;
        a0 += FEXP2(lvl2*d20);
        a1 += FEXP2(lvl2*d21);
    }
    float a = a0 + a1;
    ROW_REDUCE(a, red, tid);
    __syncthreads();
    if (tid < ROWS) {
        float t = red[0][tid] + red[1][tid] + red[2][tid] + red[3][tid];
        ratL[gbase + rc*ROWS + tid] = 1.0f / (t + 1e-9f);
    }
}

// B: sumr[m] = sum_n exp2(lvl2*d2)*ratL[n] -> ratR[m], remR[m] update.
__global__ void k_B(const float* __restrict__ tpl, const float* __restrict__ src,
                    float* __restrict__ ws, float lvl2, int first) {
    __shared__ float4 sh4[NN];
    __shared__ float red[4][ROWS];
    int bid = blockIdx.x, tid = threadIdx.x;
    int b = bid / BPB, rc = bid % BPB;
    int row = tid & 15, grp = tid >> 4;
    int gbase = b*NN, g = gbase + rc*ROWS + row;   // g indexes source point m
    const float* ratL = ws;
    float* ratR = ws + SLOT;
    float* remR = ws + 3*SLOT;
    for (int i = tid; i < NN; i += TPB) {
        const float* tp = tpl + (gbase + i)*3;
        sh4[i] = make_float4(tp[0], tp[1], tp[2], ratL[gbase + i]);
    }
    __syncthreads();
    const float* sp = src + g*3;
    float x = sp[0], y = sp[1], z = sp[2];
    float a0 = 0.f, a1 = 0.f;
#pragma unroll 8
    for (int i = 0; i < CPG; i += 2) {
        int i0 = grp + (i << 4), i1 = i0 + GRPS;
        float4 t0 = sh4[i0];
        float4 t1 = sh4[i1];
        float dx0 = t0.x-x, dy0 = t0.y-y, dz0 = t0.z-z;
        float dx1 = t1.x-x, dy1 = t1.y-y, dz1 = t1.z-z;
        float d20 = dx0*dx0 + dy0*dy0 + dz0*dz0;
        float d21 = dx1*dx1 + dy1*dy1 + dz1*dz1;
        a0 += FEXP2(lvl2*d20) * t0.w;
        a1 += FEXP2(lvl2*d21) * t1.w;
    }
    float a = a0 + a1;
    ROW_REDUCE(a, red, tid);
    __syncthreads();
    if (tid < ROWS) {
        float t = red[0][tid] + red[1][tid] + red[2][tid] + red[3][tid];
        int gg = gbase + rc*ROWS + tid;
        float rr = first ? 1.0f : remR[gg];
        float rt = rr / (t + 1e-9f);
        ratR[gg] = rt;
        remR[gg] = fmaxf(rr - rt*t, 0.0f);  // colsum = ratioR*sumr_raw (exact)
    }
}

// CA: C at level k (rowsum -> remL, cost partial) fused with A at level k+1
// (suml with post-B remR -> next ratL). d2 computed once per pair.
__global__ void k_CA(const float* __restrict__ tpl, const float* __restrict__ src,
                     float* __restrict__ ws, float lvlC, float lvlA, int firstC) {
    __shared__ float4 sh4[NN];     // {src.xyz, ratR}
    __shared__ float  shw[NN];     // remR (post-B)
    __shared__ float redr[4][ROWS], redc[4][ROWS], reda[4][ROWS];
    int bid = blockIdx.x, tid = threadIdx.x;
    int b = bid / BPB, rc = bid % BPB;
    int row = tid & 15, grp = tid >> 4;
    int gbase = b*NN, g = gbase + rc*ROWS + row;
    float* ratL = ws;
    const float* ratR = ws + SLOT;
    float* remL = ws + 2*SLOT;
    const float* remR = ws + 3*SLOT;
    float* costp = ws + 4*SLOT;
    for (int i = tid; i < NN; i += TPB) {
        const float* sp = src + (gbase + i)*3;
        sh4[i] = make_float4(sp[0], sp[1], sp[2], ratR[gbase + i]);
        shw[i] = remR[gbase + i];
    }
    __syncthreads();
    const float* tp = tpl + g*3;
    float x = tp[0], y = tp[1], z = tp[2];
    float r0 = 0.f, r1 = 0.f, c0 = 0.f, c1 = 0.f, a0 = 0.f, a1 = 0.f;
#pragma unroll 4
    for (int i = 0; i < CPG; i += 2) {
        int i0 = grp + (i << 4), i1 = i0 + GRPS;
        float4 s0 = sh4[i0];
        float4 s1 = sh4[i1];
        float w0 = shw[i0], w1 = shw[i1];
        float dx0 = x-s0.x, dy0 = y-s0.y, dz0 = z-s0.z;
        float dx1 = x-s1.x, dy1 = y-s1.y, dz1 = z-s1.z;
        float d20 = dx0*dx0 + dy0*dy0 + dz0*dz0;
        float d21 = dx1*dx1 + dy1*dy1 + dz1*dz1;
        float t0 = FEXP2(lvlC*d20) * s0.w;
        float t1 = FEXP2(lvlC*d21) * s1.w;
        r0 += t0;
        r1 += t1;
        c0 += t0 * FSQRT(fmaxf(d20, 1e-24f));
        c1 += t1 * FSQRT(fmaxf(d21, 1e-24f));
        a0 += FEXP2(lvlA*d20) * w0;
        a1 += FEXP2(lvlA*d21) * w1;
    }
    float r = r0 + r1, c = c0 + c1, a = a0 + a1;
    ROW_REDUCE(r, redr, tid);
    ROW_REDUCE(c, redc, tid);
    ROW_REDUCE(a, reda, tid);
    __syncthreads();
    float v = 0.0f;
    if (tid < ROWS) {
        float rt = redr[0][tid] + redr[1][tid] + redr[2][tid] + redr[3][tid];
        float ct = redc[0][tid] + redc[1][tid] + redc[2][tid] + redc[3][tid];
        float at = reda[0][tid] + reda[1][tid] + reda[2][tid] + reda[3][tid];
        int gg = gbase + rc*ROWS + tid;
        float rl  = firstC ? 1.0f : remL[gg];
        float rlt = ratL[gg];                 // ratioL at level k
        float rlnew = fmaxf(rl - rlt*rt, 0.0f);
        remL[gg] = rlnew;
        ratL[gg] = rlnew / (at + 1e-9f);      // ratioL at level k+1
        v = rlt * ct;                         // cost partial for this row
#pragma unroll
        for (int off = 8; off > 0; off >>= 1) v += __shfl_xor(v, off, 16);
        if (tid == 0) costp[bid] += v;
    }
}

// C9: last level (lvl=0), cost only.
__global__ void k_C9(const float* __restrict__ tpl, const float* __restrict__ src,
                     float* __restrict__ ws, float lvlC) {
    __shared__ float4 sh4[NN];
    __shared__ float redc[4][ROWS];
    int bid = blockIdx.x, tid = threadIdx.x;
    int b = bid / BPB, rc = bid % BPB;
    int row = tid & 15, grp = tid >> 4;
    int gbase = b*NN, g = gbase + rc*ROWS + row;
    const float* ratL = ws;
    const float* ratR = ws + SLOT;
    float* costp = ws + 4*SLOT;
    for (int i = tid; i < NN; i += TPB) {
        const float* sp = src + (gbase + i)*3;
        sh4[i] = make_float4(sp[0], sp[1], sp[2], ratR[gbase + i]);
    }
    __syncthreads();
    const float* tp = tpl + g*3;
    float x = tp[0], y = tp[1], z = tp[2];
    float c0 = 0.f, c1 = 0.f;
#pragma unroll 8
    for (int i = 0; i < CPG; i += 2) {
        int i0 = grp + (i << 4), i1 = i0 + GRPS;
        float4 s0 = sh4[i0];
        float4 s1 = sh4[i1];
        float dx0 = x-s0.x, dy0 = y-s0.y, dz0 = z-s0.z;
        float dx1 = x-s1.x, dy1 = y-s1.y, dz1 = z-s1.z;
        float d20 = dx0*dx0 + dy0*dy0 + dz0*dz0;
        float d21 = dx1*dx1 + dy1*dy1 + dz1*dz1;
        c0 += FEXP2(lvlC*d20) * s0.w * FSQRT(fmaxf(d20, 1e-24f));
        c1 += FEXP2(lvlC*d21) * s1.w * FSQRT(fmaxf(d21, 1e-24f));
    }
    float c = c0 + c1;
    ROW_REDUCE(c, redc, tid);
    __syncthreads();
    if (tid < ROWS) {
        float ct = redc[0][tid] + redc[1][tid] + redc[2][tid] + redc[3][tid];
        float v = ratL[gbase + rc*ROWS + tid] * ct;
#pragma unroll
        for (int off = 8; off > 0; off >>= 1) v += __shfl_xor(v, off, 16);
        if (tid == 0) costp[bid] += v;
    }
}

// Final: reduce per-block partials, scale.
__global__ void k_final(const float* __restrict__ ws, float* __restrict__ out) {
    __shared__ float swv[4];
    const float* costp = ws + 4*SLOT;
    int tid = threadIdx.x;
    float t = 0.f;
    for (int i = tid; i < NBLK; i += TPB) t += costp[i];
#pragma unroll
    for (int off = 32; off > 0; off >>= 1) t += __shfl_down(t, off, 64);
    if ((tid & 63) == 0) swv[tid >> 6] = t;
    __syncthreads();
    if (tid == 0) out[0] = (swv[0] + swv[1] + swv[2] + swv[3]) * (1.0f / (float)(BB * NN));
}

extern "C" void kernel_launch(void* const* d_in, const int* in_sizes, int n_in,
                              void* d_out, int out_size, void* d_ws, size_t ws_size,
                              hipStream_t stream) {
    const float* tpl = (const float*)d_in[0];
    const float* src = (const float*)d_in[1];
    float* ws = (float*)d_ws;
    float* out = (float*)d_out;

    // lvl2[k] = level_k * log2(e); levels = -4^(7-k) for k=0..8, 0 for k=9
    const double L2E = 1.4426950408889634;
    float lvl2[10];
    for (int k = 0; k < 9; ++k) lvl2[k] = (float)(-pow(4.0, 7 - k) * L2E);
    lvl2[9] = 0.0f;

    k_A0<<<NBLK, TPB, 0, stream>>>(tpl, src, ws, lvl2[0]);
    for (int k = 0; k < 9; ++k) {
        k_B <<<NBLK, TPB, 0, stream>>>(tpl, src, ws, lvl2[k], k == 0 ? 1 : 0);
        k_CA<<<NBLK, TPB, 0, stream>>>(tpl, src, ws, lvl2[k], lvl2[k+1], k == 0 ? 1 : 0);
    }
    k_B <<<NBLK, TPB, 0, stream>>>(tpl, src, ws, lvl2[9], 0);
    k_C9<<<NBLK, TPB, 0, stream>>>(tpl, src, ws, lvl2[9]);
    k_final<<<1, TPB, 0, stream>>>(ws, out);
}